// Round 15
// baseline (142.990 us; speedup 1.0000x reference)
//
#include <hip/hip_runtime.h>
#include <hip/hip_bf16.h>
#include <math.h>

#define NEGV -9e15f

typedef short bf16x8 __attribute__((ext_vector_type(8)));
typedef float f32x4 __attribute__((ext_vector_type(4)));

__device__ __forceinline__ unsigned short f2bf(float x) {
  unsigned u = __float_as_uint(x);
  u += 0x7fffu + ((u >> 16) & 1u);
  return (unsigned short)(u >> 16);
}

__device__ __forceinline__ unsigned pk2(float a, float b) {
  __hip_bfloat162 h = __float22bfloat162_rn(make_float2(a, b));
  unsigned u;
  __builtin_memcpy(&u, &h, 4);
  return u;
}

// branchless mish: x * n/(n+2), n = u(u+2), u = e^min(x,30)
__device__ __forceinline__ float mishf(float x) {
  float u = __expf(fminf(x, 30.0f));
  float n = u * (u + 2.0f);
  return x * __fdividef(n, n + 2.0f);
}

#define KEEP4(v) asm volatile("" : "+v"((v).x), "+v"((v).y), "+v"((v).z), "+v"((v).w))

// ---------------- prep: svec rows (bid<1024) + M composite rows (bid>=1024) ----------------
__global__ void prep_kernel(const float* __restrict__ v, float* __restrict__ s,
                            const float* __restrict__ Wb, const float* __restrict__ bb,
                            const float* __restrict__ Wo, float* __restrict__ M) {
  int bid = blockIdx.x;
  int lane = threadIdx.x;  // 64
  if (bid < 1024) {
    float4 a = *reinterpret_cast<const float4*>(v + (size_t)bid * 256 + lane * 4);
    float x = a.x + a.y + a.z + a.w;
    for (int off = 32; off; off >>= 1) x += __shfl_down(x, off);
    if (lane == 0) s[bid] = x;
  } else {
    int i = bid - 1024;  // 0..40
    if (lane >= 40) return;
    float acc = 0.0f;
    for (int k = 0; k < 160; ++k) {
      float w = (i < 40) ? Wb[i * 160 + k] : bb[k];
      acc = fmaf(w, Wo[k * 40 + lane], acc);
    }
    M[i * 40 + lane] = acc;
  }
}

// ---------------- paired GEMM via MFMA bf16: C = A @ W(perm) + bvec ----------------
__global__ __launch_bounds__(256, 2) void gemm_mfma_pair(
    const float* __restrict__ A0, const float* __restrict__ W0,
    const float* __restrict__ bv0, float* __restrict__ C0,
    const float* __restrict__ A1, const float* __restrict__ W1,
    const float* __restrict__ bv1, float* __restrict__ C1, int perm) {
  const float* A = blockIdx.z ? A1 : A0;
  const float* W = blockIdx.z ? W1 : W0;
  const float* bvec = blockIdx.z ? bv1 : bv0;
  float* C = blockIdx.z ? C1 : C0;
  __shared__ unsigned short wT[4 * 8 * 64 * 8];  // 32 KB
  int tid = threadIdx.x;
  int wv = tid >> 6, lane = tid & 63;
  int r = lane & 15, g = lane >> 4;
  int c0 = blockIdx.x * 64, r0 = blockIdx.y * 64;

  for (int idx = tid; idx < 4 * 8 * 64; idx += 256) {
    int grp = idx >> 6, lid = idx & 63;
    int n = grp >> 3, ks = grp & 7;
    int cc = c0 + n * 16 + (lid & 15);
    int kbase = ks * 32 + (lid >> 4) * 8;
    unsigned short tmp[8];
#pragma unroll
    for (int jj = 0; jj < 8; ++jj) {
      int k = kbase + jj;
      int row = perm ? ((k & 63) * 4 + (k >> 6)) : k;
      tmp[jj] = f2bf(W[row * 256 + cc]);
    }
    *reinterpret_cast<uint4*>(&wT[idx * 8]) = *reinterpret_cast<const uint4*>(tmp);
  }
  const float* xr = A + (size_t)(r0 + wv * 16 + r) * 256 + g * 8;
  float4 xa[8], xb[8];
#pragma unroll
  for (int ks = 0; ks < 8; ++ks) {
    xa[ks] = *reinterpret_cast<const float4*>(xr + ks * 32);
    xb[ks] = *reinterpret_cast<const float4*>(xr + ks * 32 + 4);
  }
  f32x4 acc[4];
#pragma unroll
  for (int n = 0; n < 4; ++n) {
    float4 b4 = *reinterpret_cast<const float4*>(bvec + c0 + n * 16 + 4 * g);
    acc[n][0] = b4.x; acc[n][1] = b4.y; acc[n][2] = b4.z; acc[n][3] = b4.w;
  }
  __syncthreads();
#pragma unroll
  for (int ks = 0; ks < 8; ++ks) {
    bf16x8 xf;
    uint4 t = {pk2(xa[ks].x, xa[ks].y), pk2(xa[ks].z, xa[ks].w),
               pk2(xb[ks].x, xb[ks].y), pk2(xb[ks].z, xb[ks].w)};
    __builtin_memcpy(&xf, &t, 16);
#pragma unroll
    for (int n = 0; n < 4; ++n) {
      bf16x8 wf = *reinterpret_cast<const bf16x8*>(&wT[((n * 8 + ks) * 64 + lane) * 8]);
      acc[n] = __builtin_amdgcn_mfma_f32_16x16x32_bf16(wf, xf, acc[n], 0, 0, 0);
    }
  }
  float* cp = C + (size_t)(r0 + wv * 16 + r) * 256 + c0;
#pragma unroll
  for (int n = 0; n < 4; ++n) {
    float4 o = {acc[n][0], acc[n][1], acc[n][2], acc[n][3]};
    *reinterpret_cast<float4*>(cp + n * 16 + 4 * g) = o;
  }
}

// ---------------- paired LN: out = LN(x0 + mish(y)) * g + be; y selects q/k ----------------
__global__ __launch_bounds__(256) void ln_pair(
    const float* __restrict__ x0q, const float* __restrict__ yq,
    const float* __restrict__ gq, const float* __restrict__ beq,
    float* __restrict__ outq,
    const float* __restrict__ x0k, const float* __restrict__ yk,
    const float* __restrict__ gk, const float* __restrict__ bek,
    float* __restrict__ outk) {
  const float* x0 = blockIdx.y ? x0k : x0q;
  const float* y  = blockIdx.y ? yk  : yq;
  const float* g  = blockIdx.y ? gk  : gq;
  const float* be = blockIdx.y ? bek : beq;
  float* out      = blockIdx.y ? outk : outq;
  __shared__ float r1[5], r2[5];
  int r = blockIdx.x, t = threadIdx.x;
  int wid = t >> 6, lane = t & 63;
  float x = x0[(size_t)r * 256 + t] + mishf(y[(size_t)r * 256 + t]);
  float a = x, b = x * x;
  for (int off = 32; off; off >>= 1) {
    a += __shfl_down(a, off);
    b += __shfl_down(b, off);
  }
  if (lane == 0) { r1[wid] = a; r2[wid] = b; }
  __syncthreads();
  if (t == 0) {
    r1[4] = r1[0] + r1[1] + r1[2] + r1[3];
    r2[4] = r2[0] + r2[1] + r2[2] + r2[3];
  }
  __syncthreads();
  float m = r1[4] * (1.0f / 256.0f);
  float var = r2[4] * (1.0f / 256.0f) - m * m;
  out[(size_t)r * 256 + t] = (x - m) * rsqrtf(var + 1e-5f) * g[t] + be[t];
}

// ---------------- fused bias path v5: weights in LDS, prefetch depth 2, pinned ----------------
#define TILE5(XA, XB, XC, XD, T) do {                                                  \
    const size_t p0 = row0 + (size_t)(T) * 16;                                         \
    bf16x8 xf0, xf1;                                                                   \
    {                                                                                  \
      uint4 t0 = {pk2((XA).x, (XA).y), pk2((XA).z, (XA).w),                            \
                  pk2((XB).x, (XB).y), pk2((XB).z, (XB).w)};                           \
      unsigned d0 = (g == 1) ? 0x00003f80u : pk2((XC).x, (XC).y);                      \
      uint4 t1 = {d0, pk2((XC).z, (XC).w), pk2((XD).x, (XD).y), pk2((XD).z, (XD).w)};  \
      __builtin_memcpy(&xf0, &t0, 16);                                                 \
      __builtin_memcpy(&xf1, &t1, 16);                                                 \
    }                                                                                  \
    if ((T) + 2 < 16) {                                                                \
      const float* xr2 = bias + (p0 + 32 + r) * 40;                                    \
      XA = *reinterpret_cast<const float4*>(xr2 + g * 8);                              \
      XB = *reinterpret_cast<const float4*>(xr2 + g * 8 + 4);                          \
      XC = *reinterpret_cast<const float4*>(xr2 + 32);                                 \
      XD = *reinterpret_cast<const float4*>(xr2 + 36);                                 \
      KEEP4(XA); KEEP4(XB); KEEP4(XC); KEEP4(XD);                                      \
    }                                                                                  \
    float cs[10];                                                                      \
    _Pragma("unroll")                                                                  \
    for (int n0 = 0; n0 < 10; ++n0) {                                                  \
      bf16x8 wa = *reinterpret_cast<const bf16x8*>(&wfL[((n0 * 2 + 0) * 64 + lane) * 8]); \
      bf16x8 wb2 = *reinterpret_cast<const bf16x8*>(&wfL[((n0 * 2 + 1) * 64 + lane) * 8]); \
      f32x4 q = {0.0f, 0.0f, 0.0f, 0.0f};                                              \
      q = __builtin_amdgcn_mfma_f32_16x16x32_bf16(wa, xf0, q, 0, 0, 0);                \
      q = __builtin_amdgcn_mfma_f32_16x16x32_bf16(wb2, xf1, q, 0, 0, 0);               \
      cs[n0] = q[0] * q[0] + q[1] * q[1] + q[2] * q[2] + q[3] * q[3];                  \
    }                                                                                  \
    float hv0 = cs[0] + cs[1] + ((g < 2) ? cs[2] : 0.0f);                              \
    float hv1 = ((g < 2) ? 0.0f : cs[2]) + cs[3] + cs[4];                              \
    float hv2 = cs[5] + cs[6] + ((g < 2) ? cs[7] : 0.0f);                              \
    float hv3 = ((g < 2) ? 0.0f : cs[7]) + cs[8] + cs[9];                              \
    hv0 += __shfl_xor(hv0, 16); hv0 += __shfl_xor(hv0, 32);                            \
    hv1 += __shfl_xor(hv1, 16); hv1 += __shfl_xor(hv1, 32);                            \
    hv2 += __shfl_xor(hv2, 16); hv2 += __shfl_xor(hv2, 32);                            \
    hv3 += __shfl_xor(hv3, 16); hv3 += __shfl_xor(hv3, 32);                            \
    float ss = (g == 0) ? hv0 : (g == 1) ? hv1 : (g == 2) ? hv2 : hv3;                 \
    diffs[(size_t)g * (1024 * 1024) + p0 + r] = sqrtf(ss);                             \
    f32x4 o0 = bo40, o1 = bo41, o2 = bo42;                                             \
    {                                                                                  \
      bf16x8 m00 = *reinterpret_cast<const bf16x8*>(&mfL[((0 * 2 + 0) * 64 + lane) * 8]); \
      bf16x8 m01 = *reinterpret_cast<const bf16x8*>(&mfL[((0 * 2 + 1) * 64 + lane) * 8]); \
      bf16x8 m10 = *reinterpret_cast<const bf16x8*>(&mfL[((1 * 2 + 0) * 64 + lane) * 8]); \
      bf16x8 m11 = *reinterpret_cast<const bf16x8*>(&mfL[((1 * 2 + 1) * 64 + lane) * 8]); \
      bf16x8 m20 = *reinterpret_cast<const bf16x8*>(&mfL[((2 * 2 + 0) * 64 + lane) * 8]); \
      bf16x8 m21 = *reinterpret_cast<const bf16x8*>(&mfL[((2 * 2 + 1) * 64 + lane) * 8]); \
      o0 = __builtin_amdgcn_mfma_f32_16x16x32_bf16(m00, xf0, o0, 0, 0, 0);             \
      o1 = __builtin_amdgcn_mfma_f32_16x16x32_bf16(m10, xf0, o1, 0, 0, 0);             \
      o2 = __builtin_amdgcn_mfma_f32_16x16x32_bf16(m20, xf0, o2, 0, 0, 0);             \
      o0 = __builtin_amdgcn_mfma_f32_16x16x32_bf16(m01, xf1, o0, 0, 0, 0);             \
      o1 = __builtin_amdgcn_mfma_f32_16x16x32_bf16(m11, xf1, o1, 0, 0, 0);             \
      o2 = __builtin_amdgcn_mfma_f32_16x16x32_bf16(m21, xf1, o2, 0, 0, 0);             \
    }                                                                                  \
    float* bp = bout + (size_t)(p0 + r) * 40;                                          \
    float4 st;                                                                         \
    st.x = mishf(o0[0]); st.y = mishf(o0[1]);                                          \
    st.z = mishf(o0[2]); st.w = mishf(o0[3]);                                          \
    *reinterpret_cast<float4*>(bp + 4 * g) = st;                                       \
    st.x = mishf(o1[0]); st.y = mishf(o1[1]);                                          \
    st.z = mishf(o1[2]); st.w = mishf(o1[3]);                                          \
    *reinterpret_cast<float4*>(bp + 16 + 4 * g) = st;                                  \
    if (g < 2) {                                                                       \
      st.x = mishf(o2[0]); st.y = mishf(o2[1]);                                        \
      st.z = mishf(o2[2]); st.w = mishf(o2[3]);                                        \
      *reinterpret_cast<float4*>(bp + 32 + 4 * g) = st;                                \
    }                                                                                  \
  } while (0)

__global__ __launch_bounds__(256, 4) void bias_mfma(
    const float* __restrict__ bias, const float* __restrict__ Wb,
    const float* __restrict__ bb, const float* __restrict__ Mmat,
    const float* __restrict__ bo, float* __restrict__ diffs,
    float* __restrict__ bout) {
  __shared__ unsigned short wfL[20 * 64 * 8];  // 20.5 KB
  __shared__ unsigned short mfL[6 * 64 * 8];   // 6 KB
  int tid = threadIdx.x;
  int wv = tid >> 6, lane = tid & 63;
  int r = lane & 15, g = lane >> 4;

  for (int idx = tid; idx < 20 * 64; idx += 256) {
    int grp = idx >> 6, lid = idx & 63;
    int n0 = grp >> 1, ks = grp & 1;
    int rr = lid & 15, gg = lid >> 4;
    int c = n0 * 16 + rr;
    unsigned short tmp[8];
#pragma unroll
    for (int jj = 0; jj < 8; ++jj) {
      int k = ks * 32 + gg * 8 + jj;
      float w = (k < 40) ? Wb[k * 160 + c] : ((k == 40) ? bb[c] : 0.0f);
      tmp[jj] = f2bf(w);
    }
    *reinterpret_cast<uint4*>(&wfL[idx * 8]) = *reinterpret_cast<const uint4*>(tmp);
  }
  for (int idx = tid; idx < 6 * 64; idx += 256) {
    int grp = idx >> 6, lid = idx & 63;
    int n = grp >> 1, ks = grp & 1;
    int rr = lid & 15, gg = lid >> 4;
    int c = n * 16 + rr;
    unsigned short tmp[8];
#pragma unroll
    for (int jj = 0; jj < 8; ++jj) {
      int k = ks * 32 + gg * 8 + jj;
      float w = (k <= 40 && c < 40) ? Mmat[k * 40 + c] : 0.0f;
      tmp[jj] = f2bf(w);
    }
    *reinterpret_cast<uint4*>(&mfL[idx * 8]) = *reinterpret_cast<const uint4*>(tmp);
  }
  f32x4 bo40, bo41, bo42;
  {
    float4 t0 = *reinterpret_cast<const float4*>(bo + 4 * g);
    float4 t1 = *reinterpret_cast<const float4*>(bo + 16 + 4 * g);
    bo40[0] = t0.x; bo40[1] = t0.y; bo40[2] = t0.z; bo40[3] = t0.w;
    bo41[0] = t1.x; bo41[1] = t1.y; bo41[2] = t1.z; bo41[3] = t1.w;
    if (g < 2) {
      float4 t2 = *reinterpret_cast<const float4*>(bo + 32 + 4 * g);
      bo42[0] = t2.x; bo42[1] = t2.y; bo42[2] = t2.z; bo42[3] = t2.w;
    } else {
      bo42[0] = 0.0f; bo42[1] = 0.0f; bo42[2] = 0.0f; bo42[3] = 0.0f;
    }
  }
  __syncthreads();

  size_t row0 = ((size_t)blockIdx.x * 4 + wv) * 256;

  // prefetch tiles 0 and 1 (two pinned register sets)
  const float* xr0 = bias + (row0 + r) * 40;
  const float* xr1 = bias + (row0 + 16 + r) * 40;
  float4 x0A = *reinterpret_cast<const float4*>(xr0 + g * 8);
  float4 x0B = *reinterpret_cast<const float4*>(xr0 + g * 8 + 4);
  float4 x0C = *reinterpret_cast<const float4*>(xr0 + 32);
  float4 x0D = *reinterpret_cast<const float4*>(xr0 + 36);
  float4 x1A = *reinterpret_cast<const float4*>(xr1 + g * 8);
  float4 x1B = *reinterpret_cast<const float4*>(xr1 + g * 8 + 4);
  float4 x1C = *reinterpret_cast<const float4*>(xr1 + 32);
  float4 x1D = *reinterpret_cast<const float4*>(xr1 + 36);
  KEEP4(x0A); KEEP4(x0B); KEEP4(x0C); KEEP4(x0D);
  KEEP4(x1A); KEEP4(x1B); KEEP4(x1C); KEEP4(x1D);

#pragma unroll 1
  for (int t = 0; t < 16; t += 2) {
    TILE5(x0A, x0B, x0C, x0D, t);
    TILE5(x1A, x1B, x1C, x1D, t + 1);
  }
}

// ---------------- fused QK^T (MFMA) + masked-softmax partials ----------------
// K^T frag table in LDS (8 KB); Q rows in regs; lane (r,g) -> S[row r][cols 16n+4g..+3].
__global__ __launch_bounds__(256) void qk_softmax(
    const float* __restrict__ pq, const float* __restrict__ pk,
    const int* __restrict__ mask, const float* __restrict__ diffs,
    const float* __restrict__ sv, float* __restrict__ mpart,
    float* __restrict__ spart, float* __restrict__ dpart) {
  __shared__ unsigned short kT[8 * 64 * 8];  // 8 KB: [(n*2+ks)*64+lane][jj]
  int tid = threadIdx.x;
  int wv = tid >> 6, lane = tid & 63;
  int r = lane & 15, g = lane >> 4;
  int k0 = blockIdx.x * 64, q0 = blockIdx.y * 64, h = blockIdx.z;

  // stage K^T fragment table: value = K[kcol][d]
  for (int idx = tid; idx < 8 * 64; idx += 256) {
    int grp = idx >> 6, lid = idx & 63;
    int n = grp >> 1, ks = grp & 1;
    int cc = n * 16 + (lid & 15);
    int dbase = ks * 32 + (lid >> 4) * 8;
    const float* kp = pk + (size_t)(k0 + cc) * 256 + h * 64 + dbase;
    unsigned short tmp[8];
#pragma unroll
    for (int jj = 0; jj < 8; ++jj) tmp[jj] = f2bf(kp[jj]);
    *reinterpret_cast<uint4*>(&kT[idx * 8]) = *reinterpret_cast<const uint4*>(tmp);
  }
  // Q row in regs: d = ks*32 + g*8 + jj
  int qq = q0 + wv * 16 + r;
  const float* qp = pq + (size_t)qq * 256 + h * 64;
  float4 qa0 = *reinterpret_cast<const float4*>(qp + g * 8);
  float4 qb0 = *reinterpret_cast<const float4*>(qp + g * 8 + 4);
  float4 qa1 = *reinterpret_cast<const float4*>(qp + 32 + g * 8);
  float4 qb1 = *reinterpret_cast<const float4*>(qp + 32 + g * 8 + 4);
  float4 s4[4];
#pragma unroll
  for (int n = 0; n < 4; ++n)
    s4[n] = *reinterpret_cast<const float4*>(sv + k0 + n * 16 + 4 * g);
  __syncthreads();

  bf16x8 xf0, xf1;
  {
    uint4 t0 = {pk2(qa0.x, qa0.y), pk2(qa0.z, qa0.w), pk2(qb0.x, qb0.y), pk2(qb0.z, qb0.w)};
    uint4 t1 = {pk2(qa1.x, qa1.y), pk2(qa1.z, qa1.w), pk2(qb1.x, qb1.y), pk2(qb1.z, qb1.w)};
    __builtin_memcpy(&xf0, &t0, 16);
    __builtin_memcpy(&xf1, &t1, 16);
  }
  f32x4 acc[4];
#pragma unroll
  for (int n = 0; n < 4; ++n) {
    f32x4 z = {0.0f, 0.0f, 0.0f, 0.0f};
    bf16x8 k0f = *reinterpret_cast<const bf16x8*>(&kT[((n * 2 + 0) * 64 + lane) * 8]);
    bf16x8 k1f = *reinterpret_cast<const bf16x8*>(&kT[((n * 2 + 1) * 64 + lane) * 8]);
    z = __builtin_amdgcn_mfma_f32_16x16x32_bf16(k0f, xf0, z, 0, 0, 0);
    acc[n] = __builtin_amdgcn_mfma_f32_16x16x32_bf16(k1f, xf1, z, 0, 0, 0);
  }
  // epilogue: masked logits -> per-row (m, sum e, sum e*s) partials
  f32x4 l[4];
  float tm = -3e38f;
#pragma unroll
  for (int n = 0; n < 4; ++n) {
    size_t base = (size_t)h * 1048576 + (size_t)qq * 1024 + k0 + n * 16 + 4 * g;
    float4 dv = *reinterpret_cast<const float4*>(diffs + base);
    int4 mv = *reinterpret_cast<const int4*>(mask + (size_t)qq * 1024 + k0 + n * 16 + 4 * g);
    l[n][0] = mv.x ? fmaf(acc[n][0], 0.125f, dv.x) : NEGV;
    l[n][1] = mv.y ? fmaf(acc[n][1], 0.125f, dv.y) : NEGV;
    l[n][2] = mv.z ? fmaf(acc[n][2], 0.125f, dv.z) : NEGV;
    l[n][3] = mv.w ? fmaf(acc[n][3], 0.125f, dv.w) : NEGV;
    tm = fmaxf(tm, fmaxf(fmaxf(l[n][0], l[n][1]), fmaxf(l[n][2], l[n][3])));
  }
  tm = fmaxf(tm, __shfl_xor(tm, 16));
  tm = fmaxf(tm, __shfl_xor(tm, 32));
  float ps = 0.0f, pd = 0.0f;
#pragma unroll
  for (int n = 0; n < 4; ++n) {
    float e0 = (l[n][0] > -1e15f) ? __expf(l[n][0] - tm) : 0.0f;
    float e1 = (l[n][1] > -1e15f) ? __expf(l[n][1] - tm) : 0.0f;
    float e2 = (l[n][2] > -1e15f) ? __expf(l[n][2] - tm) : 0.0f;
    float e3 = (l[n][3] > -1e15f) ? __expf(l[n][3] - tm) : 0.0f;
    ps += e0 + e1 + e2 + e3;
    pd = fmaf(e0, s4[n].x, pd);
    pd = fmaf(e1, s4[n].y, pd);
    pd = fmaf(e2, s4[n].z, pd);
    pd = fmaf(e3, s4[n].w, pd);
  }
  ps += __shfl_xor(ps, 16); pd += __shfl_xor(pd, 16);
  ps += __shfl_xor(ps, 32); pd += __shfl_xor(pd, 32);
  if (g == 0) {
    int plane = (h * 16 + blockIdx.x) * 1024 + qq;
    mpart[plane] = tm;
    spart[plane] = ps;
    dpart[plane] = pd;
  }
}

// ---------------- merge per-tile softmax partials -> vals_mean ----------------
__global__ void vm_reduce(const float* __restrict__ mpart,
                          const float* __restrict__ spart,
                          const float* __restrict__ dpart,
                          float* __restrict__ vm) {
  int q = blockIdx.x * 256 + threadIdx.x;
  float accum = 0.0f;
#pragma unroll
  for (int h = 0; h < 4; ++h) {
    float M = -3e38f;
#pragma unroll
    for (int kb = 0; kb < 16; ++kb)
      M = fmaxf(M, mpart[(h * 16 + kb) * 1024 + q]);
    float s = 0.0f, d = 0.0f;
#pragma unroll
    for (int kb = 0; kb < 16; ++kb) {
      int p = (h * 16 + kb) * 1024 + q;
      float sc = __expf(mpart[p] - M);
      s = fmaf(spart[p], sc, s);
      d = fmaf(dpart[p], sc, d);
    }
    accum += d / s;
  }
  vm[q] = accum * (1.0f / 1024.0f);
}

extern "C" void kernel_launch(void* const* d_in, const int* in_sizes, int n_in,
                              void* d_out, int out_size, void* d_ws, size_t ws_size,
                              hipStream_t stream) {
  const float* q     = (const float*)d_in[0];
  const float* k     = (const float*)d_in[1];
  const float* v     = (const float*)d_in[2];
  const float* bias  = (const float*)d_in[3];
  const int*   mask  = (const int*)d_in[4];
  const float* Wq    = (const float*)d_in[5];
  const float* bq    = (const float*)d_in[6];
  const float* Wk    = (const float*)d_in[7];
  const float* bk    = (const float*)d_in[8];
  const float* Wbias = (const float*)d_in[9];
  const float* bbias = (const float*)d_in[10];
  const float* Wqo   = (const float*)d_in[11];
  const float* bqo   = (const float*)d_in[12];
  const float* Wko   = (const float*)d_in[13];
  const float* bko   = (const float*)d_in[14];
  const float* g_q   = (const float*)d_in[15];
  const float* be_q  = (const float*)d_in[16];
  const float* g_k   = (const float*)d_in[17];
  const float* be_k  = (const float*)d_in[18];
  const float* Wbo   = (const float*)d_in[19];
  const float* bbo   = (const float*)d_in[20];

  float* out = (float*)d_out;
  float* ws  = (float*)d_ws;
  float* projq = ws;                 // 1024x256
  float* projk = ws + 262144;        // 1024x256
  float* qo    = ws + 524288;        // 1024x256
  float* ko    = ws + 786432;        // 1024x256
  float* diffs = ws + 1048576;       // 4 x 1024 x 1024
  float* svec  = ws + 5242880;       // 1024
  float* Mmat  = ws + 5243904;       // 41 x 40 composite
  float* mpart = ws + 5246976;       // 64 x 1024
  float* spart = ws + 5312512;       // 64 x 1024
  float* dpart = ws + 5378048;       // 64 x 1024

  float* q_out    = out;             // 1024x256
  float* k_out    = out + 262144;    // 1024x256
  float* vmean    = out + 524288;    // 1024
  float* bias_out = out + 525312;    // 1024x1024x40

  prep_kernel<<<1065, 64, 0, stream>>>(v, svec, Wbias, bbias, Wbo, Mmat);
  gemm_mfma_pair<<<dim3(4, 16, 2), 256, 0, stream>>>(q, Wq, bq, projq,
                                                     k, Wk, bk, projk, 0);
  bias_mfma<<<1024, 256, 0, stream>>>(bias, Wbias, bbias, Mmat, bbo, diffs, bias_out);
  gemm_mfma_pair<<<dim3(4, 16, 2), 256, 0, stream>>>(projq, Wqo, bqo, qo,
                                                     projk, Wko, bko, ko, 1);
  ln_pair<<<dim3(1024, 2), 256, 0, stream>>>(q, qo, g_q, be_q, q_out,
                                             k, ko, g_k, be_k, k_out);
  qk_softmax<<<dim3(16, 16, 4), 256, 0, stream>>>(projq, projk, mask, diffs,
                                                  svec, mpart, spart, dpart);
  vm_reduce<<<4, 256, 0, stream>>>(mpart, spart, dpart, vmean);
}

// Round 16
// 136.186 us; speedup vs baseline: 1.0500x; 1.0500x over previous
//
#include <hip/hip_runtime.h>
#include <hip/hip_bf16.h>
#include <math.h>

#define NEGV -9e15f

typedef short bf16x8 __attribute__((ext_vector_type(8)));
typedef float f32x4 __attribute__((ext_vector_type(4)));

__device__ __forceinline__ unsigned short f2bf(float x) {
  unsigned u = __float_as_uint(x);
  u += 0x7fffu + ((u >> 16) & 1u);
  return (unsigned short)(u >> 16);
}

__device__ __forceinline__ unsigned pk2(float a, float b) {
  __hip_bfloat162 h = __float22bfloat162_rn(make_float2(a, b));
  unsigned u;
  __builtin_memcpy(&u, &h, 4);
  return u;
}

// branchless mish: x * n/(n+2), n = u(u+2), u = e^min(x,30)
__device__ __forceinline__ float mishf(float x) {
  float u = __expf(fminf(x, 30.0f));
  float n = u * (u + 2.0f);
  return x * __fdividef(n, n + 2.0f);
}

#define KEEP4(v) asm volatile("" : "+v"((v).x), "+v"((v).y), "+v"((v).z), "+v"((v).w))

// ---------------- prep: svec rows (bid<1024) + M composite rows (bid>=1024) ----------------
__global__ void prep_kernel(const float* __restrict__ v, float* __restrict__ s,
                            const float* __restrict__ Wb, const float* __restrict__ bb,
                            const float* __restrict__ Wo, float* __restrict__ M) {
  int bid = blockIdx.x;
  int lane = threadIdx.x;  // 64
  if (bid < 1024) {
    float4 a = *reinterpret_cast<const float4*>(v + (size_t)bid * 256 + lane * 4);
    float x = a.x + a.y + a.z + a.w;
    for (int off = 32; off; off >>= 1) x += __shfl_down(x, off);
    if (lane == 0) s[bid] = x;
  } else {
    int i = bid - 1024;  // 0..40
    if (lane >= 40) return;
    float acc = 0.0f;
    for (int k = 0; k < 160; ++k) {
      float w = (i < 40) ? Wb[i * 160 + k] : bb[k];
      acc = fmaf(w, Wo[k * 40 + lane], acc);
    }
    M[i * 40 + lane] = acc;
  }
}

// ---------------- paired GEMM via MFMA bf16: C = A @ W(perm) + bvec ----------------
__global__ __launch_bounds__(256, 2) void gemm_mfma_pair(
    const float* __restrict__ A0, const float* __restrict__ W0,
    const float* __restrict__ bv0, float* __restrict__ C0,
    const float* __restrict__ A1, const float* __restrict__ W1,
    const float* __restrict__ bv1, float* __restrict__ C1, int perm) {
  const float* A = blockIdx.z ? A1 : A0;
  const float* W = blockIdx.z ? W1 : W0;
  const float* bvec = blockIdx.z ? bv1 : bv0;
  float* C = blockIdx.z ? C1 : C0;
  __shared__ unsigned short wT[4 * 8 * 64 * 8];  // 32 KB
  int tid = threadIdx.x;
  int wv = tid >> 6, lane = tid & 63;
  int r = lane & 15, g = lane >> 4;
  int c0 = blockIdx.x * 64, r0 = blockIdx.y * 64;

  for (int idx = tid; idx < 4 * 8 * 64; idx += 256) {
    int grp = idx >> 6, lid = idx & 63;
    int n = grp >> 3, ks = grp & 7;
    int cc = c0 + n * 16 + (lid & 15);
    int kbase = ks * 32 + (lid >> 4) * 8;
    unsigned short tmp[8];
#pragma unroll
    for (int jj = 0; jj < 8; ++jj) {
      int k = kbase + jj;
      int row = perm ? ((k & 63) * 4 + (k >> 6)) : k;
      tmp[jj] = f2bf(W[row * 256 + cc]);
    }
    *reinterpret_cast<uint4*>(&wT[idx * 8]) = *reinterpret_cast<const uint4*>(tmp);
  }
  const float* xr = A + (size_t)(r0 + wv * 16 + r) * 256 + g * 8;
  float4 xa[8], xb[8];
#pragma unroll
  for (int ks = 0; ks < 8; ++ks) {
    xa[ks] = *reinterpret_cast<const float4*>(xr + ks * 32);
    xb[ks] = *reinterpret_cast<const float4*>(xr + ks * 32 + 4);
  }
  f32x4 acc[4];
#pragma unroll
  for (int n = 0; n < 4; ++n) {
    float4 b4 = *reinterpret_cast<const float4*>(bvec + c0 + n * 16 + 4 * g);
    acc[n][0] = b4.x; acc[n][1] = b4.y; acc[n][2] = b4.z; acc[n][3] = b4.w;
  }
  __syncthreads();
#pragma unroll
  for (int ks = 0; ks < 8; ++ks) {
    bf16x8 xf;
    uint4 t = {pk2(xa[ks].x, xa[ks].y), pk2(xa[ks].z, xa[ks].w),
               pk2(xb[ks].x, xb[ks].y), pk2(xb[ks].z, xb[ks].w)};
    __builtin_memcpy(&xf, &t, 16);
#pragma unroll
    for (int n = 0; n < 4; ++n) {
      bf16x8 wf = *reinterpret_cast<const bf16x8*>(&wT[((n * 8 + ks) * 64 + lane) * 8]);
      acc[n] = __builtin_amdgcn_mfma_f32_16x16x32_bf16(wf, xf, acc[n], 0, 0, 0);
    }
  }
  float* cp = C + (size_t)(r0 + wv * 16 + r) * 256 + c0;
#pragma unroll
  for (int n = 0; n < 4; ++n) {
    float4 o = {acc[n][0], acc[n][1], acc[n][2], acc[n][3]};
    *reinterpret_cast<float4*>(cp + n * 16 + 4 * g) = o;
  }
}

// ---------------- paired LN: out = LN(x0 + mish(y)) * g + be; y selects q/k ----------------
__global__ __launch_bounds__(256) void ln_pair(
    const float* __restrict__ x0q, const float* __restrict__ yq,
    const float* __restrict__ gq, const float* __restrict__ beq,
    float* __restrict__ outq,
    const float* __restrict__ x0k, const float* __restrict__ yk,
    const float* __restrict__ gk, const float* __restrict__ bek,
    float* __restrict__ outk) {
  const float* x0 = blockIdx.y ? x0k : x0q;
  const float* y  = blockIdx.y ? yk  : yq;
  const float* g  = blockIdx.y ? gk  : gq;
  const float* be = blockIdx.y ? bek : beq;
  float* out      = blockIdx.y ? outk : outq;
  __shared__ float r1[5], r2[5];
  int r = blockIdx.x, t = threadIdx.x;
  int wid = t >> 6, lane = t & 63;
  float x = x0[(size_t)r * 256 + t] + mishf(y[(size_t)r * 256 + t]);
  float a = x, b = x * x;
  for (int off = 32; off; off >>= 1) {
    a += __shfl_down(a, off);
    b += __shfl_down(b, off);
  }
  if (lane == 0) { r1[wid] = a; r2[wid] = b; }
  __syncthreads();
  if (t == 0) {
    r1[4] = r1[0] + r1[1] + r1[2] + r1[3];
    r2[4] = r2[0] + r2[1] + r2[2] + r2[3];
  }
  __syncthreads();
  float m = r1[4] * (1.0f / 256.0f);
  float var = r2[4] * (1.0f / 256.0f) - m * m;
  out[(size_t)r * 256 + t] = (x - m) * rsqrtf(var + 1e-5f) * g[t] + be[t];
}

// ---------------- fused bias path v6: 512-thread blocks, shared LDS tables, 16 waves/CU ----
#define TILE5(XA, XB, XC, XD, T) do {                                                  \
    const size_t p0 = row0 + (size_t)(T) * 16;                                         \
    bf16x8 xf0, xf1;                                                                   \
    {                                                                                  \
      uint4 t0 = {pk2((XA).x, (XA).y), pk2((XA).z, (XA).w),                            \
                  pk2((XB).x, (XB).y), pk2((XB).z, (XB).w)};                           \
      unsigned d0 = (g == 1) ? 0x00003f80u : pk2((XC).x, (XC).y);                      \
      uint4 t1 = {d0, pk2((XC).z, (XC).w), pk2((XD).x, (XD).y), pk2((XD).z, (XD).w)};  \
      __builtin_memcpy(&xf0, &t0, 16);                                                 \
      __builtin_memcpy(&xf1, &t1, 16);                                                 \
    }                                                                                  \
    if ((T) + 2 < 16) {                                                                \
      const float* xr2 = bias + (p0 + 32 + r) * 40;                                    \
      XA = *reinterpret_cast<const float4*>(xr2 + g * 8);                              \
      XB = *reinterpret_cast<const float4*>(xr2 + g * 8 + 4);                          \
      XC = *reinterpret_cast<const float4*>(xr2 + 32);                                 \
      XD = *reinterpret_cast<const float4*>(xr2 + 36);                                 \
      KEEP4(XA); KEEP4(XB); KEEP4(XC); KEEP4(XD);                                      \
    }                                                                                  \
    float cs[10];                                                                      \
    _Pragma("unroll")                                                                  \
    for (int n0 = 0; n0 < 10; ++n0) {                                                  \
      bf16x8 wa = *reinterpret_cast<const bf16x8*>(&wfL[((n0 * 2 + 0) * 64 + lane) * 8]); \
      bf16x8 wb2 = *reinterpret_cast<const bf16x8*>(&wfL[((n0 * 2 + 1) * 64 + lane) * 8]); \
      f32x4 q = {0.0f, 0.0f, 0.0f, 0.0f};                                              \
      q = __builtin_amdgcn_mfma_f32_16x16x32_bf16(wa, xf0, q, 0, 0, 0);                \
      q = __builtin_amdgcn_mfma_f32_16x16x32_bf16(wb2, xf1, q, 0, 0, 0);               \
      cs[n0] = q[0] * q[0] + q[1] * q[1] + q[2] * q[2] + q[3] * q[3];                  \
    }                                                                                  \
    float hv0 = cs[0] + cs[1] + ((g < 2) ? cs[2] : 0.0f);                              \
    float hv1 = ((g < 2) ? 0.0f : cs[2]) + cs[3] + cs[4];                              \
    float hv2 = cs[5] + cs[6] + ((g < 2) ? cs[7] : 0.0f);                              \
    float hv3 = ((g < 2) ? 0.0f : cs[7]) + cs[8] + cs[9];                              \
    hv0 += __shfl_xor(hv0, 16); hv0 += __shfl_xor(hv0, 32);                            \
    hv1 += __shfl_xor(hv1, 16); hv1 += __shfl_xor(hv1, 32);                            \
    hv2 += __shfl_xor(hv2, 16); hv2 += __shfl_xor(hv2, 32);                            \
    hv3 += __shfl_xor(hv3, 16); hv3 += __shfl_xor(hv3, 32);                            \
    float ss = (g == 0) ? hv0 : (g == 1) ? hv1 : (g == 2) ? hv2 : hv3;                 \
    diffs[(size_t)g * (1024 * 1024) + p0 + r] = sqrtf(ss);                             \
    f32x4 o0 = bo40, o1 = bo41, o2 = bo42;                                             \
    {                                                                                  \
      bf16x8 m00 = *reinterpret_cast<const bf16x8*>(&mfL[((0 * 2 + 0) * 64 + lane) * 8]); \
      bf16x8 m01 = *reinterpret_cast<const bf16x8*>(&mfL[((0 * 2 + 1) * 64 + lane) * 8]); \
      bf16x8 m10 = *reinterpret_cast<const bf16x8*>(&mfL[((1 * 2 + 0) * 64 + lane) * 8]); \
      bf16x8 m11 = *reinterpret_cast<const bf16x8*>(&mfL[((1 * 2 + 1) * 64 + lane) * 8]); \
      bf16x8 m20 = *reinterpret_cast<const bf16x8*>(&mfL[((2 * 2 + 0) * 64 + lane) * 8]); \
      bf16x8 m21 = *reinterpret_cast<const bf16x8*>(&mfL[((2 * 2 + 1) * 64 + lane) * 8]); \
      o0 = __builtin_amdgcn_mfma_f32_16x16x32_bf16(m00, xf0, o0, 0, 0, 0);             \
      o1 = __builtin_amdgcn_mfma_f32_16x16x32_bf16(m10, xf0, o1, 0, 0, 0);             \
      o2 = __builtin_amdgcn_mfma_f32_16x16x32_bf16(m20, xf0, o2, 0, 0, 0);             \
      o0 = __builtin_amdgcn_mfma_f32_16x16x32_bf16(m01, xf1, o0, 0, 0, 0);             \
      o1 = __builtin_amdgcn_mfma_f32_16x16x32_bf16(m11, xf1, o1, 0, 0, 0);             \
      o2 = __builtin_amdgcn_mfma_f32_16x16x32_bf16(m21, xf1, o2, 0, 0, 0);             \
    }                                                                                  \
    float* bp = bout + (size_t)(p0 + r) * 40;                                          \
    float4 st;                                                                         \
    st.x = mishf(o0[0]); st.y = mishf(o0[1]);                                          \
    st.z = mishf(o0[2]); st.w = mishf(o0[3]);                                          \
    *reinterpret_cast<float4*>(bp + 4 * g) = st;                                       \
    st.x = mishf(o1[0]); st.y = mishf(o1[1]);                                          \
    st.z = mishf(o1[2]); st.w = mishf(o1[3]);                                          \
    *reinterpret_cast<float4*>(bp + 16 + 4 * g) = st;                                  \
    if (g < 2) {                                                                       \
      st.x = mishf(o2[0]); st.y = mishf(o2[1]);                                        \
      st.z = mishf(o2[2]); st.w = mishf(o2[3]);                                        \
      *reinterpret_cast<float4*>(bp + 32 + 4 * g) = st;                                \
    }                                                                                  \
  } while (0)

__global__ __launch_bounds__(512, 4) void bias_mfma(
    const float* __restrict__ bias, const float* __restrict__ Wb,
    const float* __restrict__ bb, const float* __restrict__ Mmat,
    const float* __restrict__ bo, float* __restrict__ diffs,
    float* __restrict__ bout) {
  __shared__ unsigned short wfL[20 * 64 * 8];  // 20.5 KB (shared by 8 waves)
  __shared__ unsigned short mfL[6 * 64 * 8];   // 6 KB
  int tid = threadIdx.x;
  int wv = tid >> 6, lane = tid & 63;
  int r = lane & 15, g = lane >> 4;

  for (int idx = tid; idx < 20 * 64; idx += 512) {
    int grp = idx >> 6, lid = idx & 63;
    int n0 = grp >> 1, ks = grp & 1;
    int rr = lid & 15, gg = lid >> 4;
    int c = n0 * 16 + rr;
    unsigned short tmp[8];
#pragma unroll
    for (int jj = 0; jj < 8; ++jj) {
      int k = ks * 32 + gg * 8 + jj;
      float w = (k < 40) ? Wb[k * 160 + c] : ((k == 40) ? bb[c] : 0.0f);
      tmp[jj] = f2bf(w);
    }
    *reinterpret_cast<uint4*>(&wfL[idx * 8]) = *reinterpret_cast<const uint4*>(tmp);
  }
  for (int idx = tid; idx < 6 * 64; idx += 512) {
    int grp = idx >> 6, lid = idx & 63;
    int n = grp >> 1, ks = grp & 1;
    int rr = lid & 15, gg = lid >> 4;
    int c = n * 16 + rr;
    unsigned short tmp[8];
#pragma unroll
    for (int jj = 0; jj < 8; ++jj) {
      int k = ks * 32 + gg * 8 + jj;
      float w = (k <= 40 && c < 40) ? Mmat[k * 40 + c] : 0.0f;
      tmp[jj] = f2bf(w);
    }
    *reinterpret_cast<uint4*>(&mfL[idx * 8]) = *reinterpret_cast<const uint4*>(tmp);
  }
  f32x4 bo40, bo41, bo42;
  {
    float4 t0 = *reinterpret_cast<const float4*>(bo + 4 * g);
    float4 t1 = *reinterpret_cast<const float4*>(bo + 16 + 4 * g);
    bo40[0] = t0.x; bo40[1] = t0.y; bo40[2] = t0.z; bo40[3] = t0.w;
    bo41[0] = t1.x; bo41[1] = t1.y; bo41[2] = t1.z; bo41[3] = t1.w;
    if (g < 2) {
      float4 t2 = *reinterpret_cast<const float4*>(bo + 32 + 4 * g);
      bo42[0] = t2.x; bo42[1] = t2.y; bo42[2] = t2.z; bo42[3] = t2.w;
    } else {
      bo42[0] = 0.0f; bo42[1] = 0.0f; bo42[2] = 0.0f; bo42[3] = 0.0f;
    }
  }
  __syncthreads();

  size_t row0 = ((size_t)blockIdx.x * 8 + wv) * 256;  // 512 blocks x 8 waves x 256 rows

  // prefetch tiles 0 and 1 (two pinned register sets)
  const float* xr0 = bias + (row0 + r) * 40;
  const float* xr1 = bias + (row0 + 16 + r) * 40;
  float4 x0A = *reinterpret_cast<const float4*>(xr0 + g * 8);
  float4 x0B = *reinterpret_cast<const float4*>(xr0 + g * 8 + 4);
  float4 x0C = *reinterpret_cast<const float4*>(xr0 + 32);
  float4 x0D = *reinterpret_cast<const float4*>(xr0 + 36);
  float4 x1A = *reinterpret_cast<const float4*>(xr1 + g * 8);
  float4 x1B = *reinterpret_cast<const float4*>(xr1 + g * 8 + 4);
  float4 x1C = *reinterpret_cast<const float4*>(xr1 + 32);
  float4 x1D = *reinterpret_cast<const float4*>(xr1 + 36);
  KEEP4(x0A); KEEP4(x0B); KEEP4(x0C); KEEP4(x0D);
  KEEP4(x1A); KEEP4(x1B); KEEP4(x1C); KEEP4(x1D);

#pragma unroll 1
  for (int t = 0; t < 16; t += 2) {
    TILE5(x0A, x0B, x0C, x0D, t);
    TILE5(x1A, x1B, x1C, x1D, t + 1);
  }
}

// ---------------- fused QK^T (MFMA) + masked-softmax partials ----------------
__global__ __launch_bounds__(256) void qk_softmax(
    const float* __restrict__ pq, const float* __restrict__ pk,
    const int* __restrict__ mask, const float* __restrict__ diffs,
    const float* __restrict__ sv, float* __restrict__ mpart,
    float* __restrict__ spart, float* __restrict__ dpart) {
  __shared__ unsigned short kT[8 * 64 * 8];  // 8 KB
  int tid = threadIdx.x;
  int wv = tid >> 6, lane = tid & 63;
  int r = lane & 15, g = lane >> 4;
  int k0 = blockIdx.x * 64, q0 = blockIdx.y * 64, h = blockIdx.z;

  for (int idx = tid; idx < 8 * 64; idx += 256) {
    int grp = idx >> 6, lid = idx & 63;
    int n = grp >> 1, ks = grp & 1;
    int cc = n * 16 + (lid & 15);
    int dbase = ks * 32 + (lid >> 4) * 8;
    const float* kp = pk + (size_t)(k0 + cc) * 256 + h * 64 + dbase;
    unsigned short tmp[8];
#pragma unroll
    for (int jj = 0; jj < 8; ++jj) tmp[jj] = f2bf(kp[jj]);
    *reinterpret_cast<uint4*>(&kT[idx * 8]) = *reinterpret_cast<const uint4*>(tmp);
  }
  int qq = q0 + wv * 16 + r;
  const float* qp = pq + (size_t)qq * 256 + h * 64;
  float4 qa0 = *reinterpret_cast<const float4*>(qp + g * 8);
  float4 qb0 = *reinterpret_cast<const float4*>(qp + g * 8 + 4);
  float4 qa1 = *reinterpret_cast<const float4*>(qp + 32 + g * 8);
  float4 qb1 = *reinterpret_cast<const float4*>(qp + 32 + g * 8 + 4);
  float4 s4[4];
#pragma unroll
  for (int n = 0; n < 4; ++n)
    s4[n] = *reinterpret_cast<const float4*>(sv + k0 + n * 16 + 4 * g);
  __syncthreads();

  bf16x8 xf0, xf1;
  {
    uint4 t0 = {pk2(qa0.x, qa0.y), pk2(qa0.z, qa0.w), pk2(qb0.x, qb0.y), pk2(qb0.z, qb0.w)};
    uint4 t1 = {pk2(qa1.x, qa1.y), pk2(qa1.z, qa1.w), pk2(qb1.x, qb1.y), pk2(qb1.z, qb1.w)};
    __builtin_memcpy(&xf0, &t0, 16);
    __builtin_memcpy(&xf1, &t1, 16);
  }
  f32x4 acc[4];
#pragma unroll
  for (int n = 0; n < 4; ++n) {
    f32x4 z = {0.0f, 0.0f, 0.0f, 0.0f};
    bf16x8 k0f = *reinterpret_cast<const bf16x8*>(&kT[((n * 2 + 0) * 64 + lane) * 8]);
    bf16x8 k1f = *reinterpret_cast<const bf16x8*>(&kT[((n * 2 + 1) * 64 + lane) * 8]);
    z = __builtin_amdgcn_mfma_f32_16x16x32_bf16(k0f, xf0, z, 0, 0, 0);
    acc[n] = __builtin_amdgcn_mfma_f32_16x16x32_bf16(k1f, xf1, z, 0, 0, 0);
  }
  f32x4 l[4];
  float tm = -3e38f;
#pragma unroll
  for (int n = 0; n < 4; ++n) {
    size_t base = (size_t)h * 1048576 + (size_t)qq * 1024 + k0 + n * 16 + 4 * g;
    float4 dv = *reinterpret_cast<const float4*>(diffs + base);
    int4 mv = *reinterpret_cast<const int4*>(mask + (size_t)qq * 1024 + k0 + n * 16 + 4 * g);
    l[n][0] = mv.x ? fmaf(acc[n][0], 0.125f, dv.x) : NEGV;
    l[n][1] = mv.y ? fmaf(acc[n][1], 0.125f, dv.y) : NEGV;
    l[n][2] = mv.z ? fmaf(acc[n][2], 0.125f, dv.z) : NEGV;
    l[n][3] = mv.w ? fmaf(acc[n][3], 0.125f, dv.w) : NEGV;
    tm = fmaxf(tm, fmaxf(fmaxf(l[n][0], l[n][1]), fmaxf(l[n][2], l[n][3])));
  }
  tm = fmaxf(tm, __shfl_xor(tm, 16));
  tm = fmaxf(tm, __shfl_xor(tm, 32));
  float ps = 0.0f, pd = 0.0f;
#pragma unroll
  for (int n = 0; n < 4; ++n) {
    float e0 = (l[n][0] > -1e15f) ? __expf(l[n][0] - tm) : 0.0f;
    float e1 = (l[n][1] > -1e15f) ? __expf(l[n][1] - tm) : 0.0f;
    float e2 = (l[n][2] > -1e15f) ? __expf(l[n][2] - tm) : 0.0f;
    float e3 = (l[n][3] > -1e15f) ? __expf(l[n][3] - tm) : 0.0f;
    ps += e0 + e1 + e2 + e3;
    pd = fmaf(e0, s4[n].x, pd);
    pd = fmaf(e1, s4[n].y, pd);
    pd = fmaf(e2, s4[n].z, pd);
    pd = fmaf(e3, s4[n].w, pd);
  }
  ps += __shfl_xor(ps, 16); pd += __shfl_xor(pd, 16);
  ps += __shfl_xor(ps, 32); pd += __shfl_xor(pd, 32);
  if (g == 0) {
    int plane = (h * 16 + blockIdx.x) * 1024 + qq;
    mpart[plane] = tm;
    spart[plane] = ps;
    dpart[plane] = pd;
  }
}

// ---------------- merge per-tile softmax partials -> vals_mean ----------------
__global__ void vm_reduce(const float* __restrict__ mpart,
                          const float* __restrict__ spart,
                          const float* __restrict__ dpart,
                          float* __restrict__ vm) {
  int q = blockIdx.x * 256 + threadIdx.x;
  float accum = 0.0f;
#pragma unroll
  for (int h = 0; h < 4; ++h) {
    float M = -3e38f;
#pragma unroll
    for (int kb = 0; kb < 16; ++kb)
      M = fmaxf(M, mpart[(h * 16 + kb) * 1024 + q]);
    float s = 0.0f, d = 0.0f;
#pragma unroll
    for (int kb = 0; kb < 16; ++kb) {
      int p = (h * 16 + kb) * 1024 + q;
      float sc = __expf(mpart[p] - M);
      s = fmaf(spart[p], sc, s);
      d = fmaf(dpart[p], sc, d);
    }
    accum += d / s;
  }
  vm[q] = accum * (1.0f / 1024.0f);
}

extern "C" void kernel_launch(void* const* d_in, const int* in_sizes, int n_in,
                              void* d_out, int out_size, void* d_ws, size_t ws_size,
                              hipStream_t stream) {
  const float* q     = (const float*)d_in[0];
  const float* k     = (const float*)d_in[1];
  const float* v     = (const float*)d_in[2];
  const float* bias  = (const float*)d_in[3];
  const int*   mask  = (const int*)d_in[4];
  const float* Wq    = (const float*)d_in[5];
  const float* bq    = (const float*)d_in[6];
  const float* Wk    = (const float*)d_in[7];
  const float* bk    = (const float*)d_in[8];
  const float* Wbias = (const float*)d_in[9];
  const float* bbias = (const float*)d_in[10];
  const float* Wqo   = (const float*)d_in[11];
  const float* bqo   = (const float*)d_in[12];
  const float* Wko   = (const float*)d_in[13];
  const float* bko   = (const float*)d_in[14];
  const float* g_q   = (const float*)d_in[15];
  const float* be_q  = (const float*)d_in[16];
  const float* g_k   = (const float*)d_in[17];
  const float* be_k  = (const float*)d_in[18];
  const float* Wbo   = (const float*)d_in[19];
  const float* bbo   = (const float*)d_in[20];

  float* out = (float*)d_out;
  float* ws  = (float*)d_ws;
  float* projq = ws;                 // 1024x256
  float* projk = ws + 262144;        // 1024x256
  float* qo    = ws + 524288;        // 1024x256
  float* ko    = ws + 786432;        // 1024x256
  float* diffs = ws + 1048576;       // 4 x 1024 x 1024
  float* svec  = ws + 5242880;       // 1024
  float* Mmat  = ws + 5243904;       // 41 x 40 composite
  float* mpart = ws + 5246976;       // 64 x 1024
  float* spart = ws + 5312512;       // 64 x 1024
  float* dpart = ws + 5378048;       // 64 x 1024

  float* q_out    = out;             // 1024x256
  float* k_out    = out + 262144;    // 1024x256
  float* vmean    = out + 524288;    // 1024
  float* bias_out = out + 525312;    // 1024x1024x40

  prep_kernel<<<1065, 64, 0, stream>>>(v, svec, Wbias, bbias, Wbo, Mmat);
  gemm_mfma_pair<<<dim3(4, 16, 2), 256, 0, stream>>>(q, Wq, bq, projq,
                                                     k, Wk, bk, projk, 0);
  bias_mfma<<<512, 512, 0, stream>>>(bias, Wbias, bbias, Mmat, bbo, diffs, bias_out);
  gemm_mfma_pair<<<dim3(4, 16, 2), 256, 0, stream>>>(projq, Wqo, bqo, qo,
                                                     projk, Wko, bko, ko, 1);
  ln_pair<<<dim3(1024, 2), 256, 0, stream>>>(q, qo, g_q, be_q, q_out,
                                             k, ko, g_k, be_k, k_out);
  qk_softmax<<<dim3(16, 16, 4), 256, 0, stream>>>(projq, projk, mask, diffs,
                                                  svec, mpart, spart, dpart);
  vm_reduce<<<4, 256, 0, stream>>>(mpart, spart, dpart, vmean);
}